// Round 14
// baseline (1369.435 us; speedup 1.0000x reference)
//
#include <hip/hip_runtime.h>
#include <math.h>

#define S_TOT 2048
#define DMODEL 768
#define QKVD 2304
#define NHEAD 8
#define HDIM 96
#define FFDIM 2048
#define VOCAB 32000
#define MAXLEN_C 512
#define POL_CHUNK 3200   // fallback path only
#define VLT_LD 2080      // 2048 + 32 pad so k-frag overreads stay in-bounds
#define NEG_BIG (-3.0e38f)
#define M_INIT (-1.0e30f)
#define QK_SCALE 0.10206207261596575f  // 1/sqrt(96)

typedef __bf16 bf16x8 __attribute__((ext_vector_type(8)));
typedef float f32x4 __attribute__((ext_vector_type(4)));
typedef unsigned short u16x8 __attribute__((ext_vector_type(8)));
typedef unsigned short u16x4 __attribute__((ext_vector_type(4)));

__device__ __forceinline__ float gelu_exact(float x) {
  return 0.5f * x * (1.0f + erff(x * 0.70710678118654752f));
}

__device__ __forceinline__ float bf2f(unsigned short u) {
  union { unsigned int i; float f; } v;
  v.i = ((unsigned int)u) << 16;
  return v.f;
}

__device__ __forceinline__ unsigned short f2bf(float f) {
  union { float f; unsigned int i; } v;
  v.f = f;
  unsigned int x = v.i;
  return (unsigned short)((x + 0x7fffu + ((x >> 16) & 1u)) >> 16);  // RNE
}

__device__ __forceinline__ unsigned int pack2bf(float a, float b) {
  return (unsigned int)f2bf(a) | ((unsigned int)f2bf(b) << 16);
}

// async global->LDS, 16B per lane; dst must be wave-uniform base
__device__ __forceinline__ void gload_lds16(const unsigned short* g, unsigned short* l) {
  __builtin_amdgcn_global_load_lds(
      (const __attribute__((address_space(1))) unsigned int*)g,
      (__attribute__((address_space(3))) unsigned int*)l, 16, 0, 0);
}

// ---------------------------------------------------------------------------
// Embed: x[p] = se[p] + pe[p/T] + th[p%T] for p < MAXLEN*T, else 0 (f32 out)
// ---------------------------------------------------------------------------
__global__ __launch_bounds__(256) void embed_kernel(
    const float* __restrict__ se, const float* __restrict__ pe,
    const float* __restrict__ th, const int* __restrict__ ntt,
    float* __restrict__ X) {
  int idx = blockIdx.x * 256 + threadIdx.x;
  if (idx >= S_TOT * DMODEL) return;
  int p = idx / DMODEL;
  int d = idx - p * DMODEL;
  int T = ntt[0] + 1;
  float v = 0.0f;
  if (p < MAXLEN_C * T) {
    v = se[idx] + pe[(p / T) * DMODEL + d] + th[(p % T) * DMODEL + d];
  }
  X[idx] = v;
}

// ---------------------------------------------------------------------------
// LayerNorm f32 in -> bf16 out. One block (256 thr) per row, 3 elems/thread.
// ---------------------------------------------------------------------------
__global__ __launch_bounds__(256) void ln_bf_kernel(
    const float* __restrict__ X, const float* __restrict__ g,
    const float* __restrict__ b, unsigned short* __restrict__ Y) {
  __shared__ float red[4];
  const int row = blockIdx.x;
  const int tid = threadIdx.x;
  const float* x = X + (size_t)row * DMODEL;
  float v0 = x[tid], v1 = x[tid + 256], v2 = x[tid + 512];
  float s = v0 + v1 + v2;
  for (int o = 32; o; o >>= 1) s += __shfl_xor(s, o);
  if ((tid & 63) == 0) red[tid >> 6] = s;
  __syncthreads();
  float mean = (red[0] + red[1] + red[2] + red[3]) * (1.0f / DMODEL);
  float d0 = v0 - mean, d1 = v1 - mean, d2 = v2 - mean;
  float s2 = d0 * d0 + d1 * d1 + d2 * d2;
  for (int o = 32; o; o >>= 1) s2 += __shfl_xor(s2, o);
  __syncthreads();
  if ((tid & 63) == 0) red[tid >> 6] = s2;
  __syncthreads();
  float var = (red[0] + red[1] + red[2] + red[3]) * (1.0f / DMODEL);
  float rstd = rsqrtf(var + 1e-4f);
  unsigned short* y = Y + (size_t)row * DMODEL;
  y[tid]       = f2bf(d0 * rstd * g[tid]       + b[tid]);
  y[tid + 256] = f2bf(d1 * rstd * g[tid + 256] + b[tid + 256]);
  y[tid + 512] = f2bf(d2 * rstd * g[tid + 512] + b[tid + 512]);
}

// ---------------------------------------------------------------------------
// f32 -> bf16 convert, n divisible by 4
// ---------------------------------------------------------------------------
__global__ __launch_bounds__(256) void cvt_kernel(
    const float* __restrict__ s, unsigned short* __restrict__ d, int n) {
  int i = (blockIdx.x * 256 + threadIdx.x) * 4;
  if (i >= n) return;
  float4 v = *(const float4*)(s + i);
  u16x4 o;
  o[0] = f2bf(v.x); o[1] = f2bf(v.y); o[2] = f2bf(v.z); o[3] = f2bf(v.w);
  *(u16x4*)(d + i) = o;
}

// ---------------------------------------------------------------------------
// bf16 MFMA NT GEMM, 128x128 tile, BK=32, 4 waves (fallback small-ws path).
// ---------------------------------------------------------------------------
__global__ __launch_bounds__(256) void gemm_bf16_kernel(
    const unsigned short* __restrict__ A, const unsigned short* __restrict__ B,
    const float* __restrict__ bias, const float* __restrict__ res,
    void* __restrict__ Cout, int M, int N, int K, int ldc, int act, int outbf,
    int swiz) {
  __shared__ __align__(16) unsigned short As[3 * 4096];
  __shared__ __align__(16) unsigned short Bs[3 * 4096];
  const int t = threadIdx.x;
  const int w = t >> 6, l = t & 63;
  int n_blk, m_blk;
  if (swiz) {
    const int g = blockIdx.x;
    const int chunk = gridDim.x >> 3;
    const int logical = (g & 7) * chunk + (g >> 3);
    m_blk = logical & 15;
    n_blk = logical >> 4;
  } else {
    n_blk = blockIdx.x; m_blk = blockIdx.y;
  }
  const int n0 = n_blk * 128, i0 = m_blk * 128;
  const int wr = w >> 1, wc = w & 1;
  const int lr = l & 15;
  const int koff = (l >> 4) * 8;

  f32x4 acc[4][4] = {};

  const int srow = t >> 2;
  const int scol = (t & 3) * 8;
  const unsigned short* Ag = A + (size_t)(i0 + srow) * K + scol;
  const unsigned short* Bg = B + (size_t)(n0 + srow) * K + scol;
  const int lo0 = (w << 9);
  const int lo1 = 2048 + (w << 9);

#define STAGE128(buf, k0)                                        \
  do {                                                           \
    gload_lds16(Ag + (k0), &As[(buf) * 4096 + lo0]);             \
    gload_lds16(Ag + (size_t)64 * K + (k0), &As[(buf) * 4096 + lo1]); \
    gload_lds16(Bg + (k0), &Bs[(buf) * 4096 + lo0]);             \
    gload_lds16(Bg + (size_t)64 * K + (k0), &Bs[(buf) * 4096 + lo1]); \
  } while (0)

#define COMPUTE128(buf)                                                   \
  do {                                                                    \
    const unsigned short* Ab = &As[(buf) * 4096];                         \
    const unsigned short* Bb = &Bs[(buf) * 4096];                         \
    bf16x8 af[4], bfr[4];                                                 \
    _Pragma("unroll") for (int fi = 0; fi < 4; ++fi)                      \
        af[fi] = *(const bf16x8*)&Ab[(wr * 64 + fi * 16 + lr) * 32 + koff]; \
    _Pragma("unroll") for (int fj = 0; fj < 4; ++fj)                      \
        bfr[fj] = *(const bf16x8*)&Bb[(wc * 64 + fj * 16 + lr) * 32 + koff]; \
    _Pragma("unroll") for (int fi = 0; fi < 4; ++fi)                      \
      _Pragma("unroll") for (int fj = 0; fj < 4; ++fj)                    \
          acc[fi][fj] = __builtin_amdgcn_mfma_f32_16x16x32_bf16(          \
              bfr[fj], af[fi], acc[fi][fj], 0, 0, 0);                     \
  } while (0)

  const int nt = K >> 5;
  STAGE128(0, 0);
  if (nt > 1) STAGE128(1, 32);
  for (int tt = 0; tt < nt; ++tt) {
    __builtin_amdgcn_s_barrier();
    if (tt + 2 < nt) {
      STAGE128((tt + 2) % 3, (tt + 2) << 5);
      asm volatile("s_waitcnt vmcnt(8)" ::: "memory");
    } else if (tt + 1 < nt) {
      asm volatile("s_waitcnt vmcnt(4)" ::: "memory");
    } else {
      asm volatile("s_waitcnt vmcnt(0)" ::: "memory");
    }
    __builtin_amdgcn_sched_barrier(0);
    COMPUTE128(tt % 3);
    __builtin_amdgcn_sched_barrier(0);
  }

  const int mloc = l & 15, ng = (l >> 4) * 4;
#pragma unroll
  for (int fi = 0; fi < 4; ++fi) {
    const int i = i0 + wr * 64 + fi * 16 + mloc;
    const size_t rowbase = (size_t)i * ldc;
#pragma unroll
    for (int fj = 0; fj < 4; ++fj) {
      const int nb = n0 + wc * 64 + fj * 16 + ng;
      float z0 = acc[fi][fj][0], z1 = acc[fi][fj][1];
      float z2 = acc[fi][fj][2], z3 = acc[fi][fj][3];
      if (bias) {
        float4 bv = *(const float4*)(bias + nb);
        z0 += bv.x; z1 += bv.y; z2 += bv.z; z3 += bv.w;
      }
      if (act) {
        z0 = gelu_exact(z0); z1 = gelu_exact(z1);
        z2 = gelu_exact(z2); z3 = gelu_exact(z3);
      }
      if (res) {
        float4 rv = *(const float4*)(res + rowbase + nb);
        z0 += rv.x; z1 += rv.y; z2 += rv.z; z3 += rv.w;
      }
      if (outbf) {
        u16x4 o;
        o[0] = f2bf(z0); o[1] = f2bf(z1); o[2] = f2bf(z2); o[3] = f2bf(z3);
        *(u16x4*)((unsigned short*)Cout + rowbase + nb) = o;
      } else {
        *(float4*)((float*)Cout + rowbase + nb) = make_float4(z0, z1, z2, z3);
      }
    }
  }
#undef STAGE128
#undef COMPUTE128
}

// ---------------------------------------------------------------------------
// bf16 MFMA NT GEMM, 256(M)x128(N) tile, BK=32, 8 waves (512 thr) — r10
// measured-best policy config: 2-buffer 1-ahead, vmcnt(3), two barriers.
// XCD-chunk swizzle, m-fastest (M/256 == 8).
// ---------------------------------------------------------------------------
__global__ __launch_bounds__(512) void gemm256_bf16_kernel(
    const unsigned short* __restrict__ A, const unsigned short* __restrict__ B,
    void* __restrict__ Cout, int M, int N, int K, int ldc) {
  __shared__ __align__(16) unsigned short As[2 * 8192];  // 256 x 32 per buf
  __shared__ __align__(16) unsigned short Bs[2 * 4096];  // 128 x 32 per buf
  const int t = threadIdx.x;
  const int w = t >> 6, l = t & 63;
  const int g = blockIdx.x;
  const int chunk = gridDim.x >> 3;
  const int logical = (g & 7) * chunk + (g >> 3);
  const int m_blk = logical & 7;    // M/256 == 8
  const int n_blk = logical >> 3;
  const int n0 = n_blk * 128, i0 = m_blk * 256;
  const int wr = w >> 1;            // 0..3 -> 64-row quarter
  const int wc = w & 1;             // 0..1 -> 64-col half
  const int lr = l & 15;
  const int koff = (l >> 4) * 8;

  f32x4 acc[4][4] = {};

  const int srow = t >> 2;          // 0..127
  const int scol = (t & 3) * 8;
  const unsigned short* Ag = A + (size_t)(i0 + srow) * K + scol;
  const unsigned short* Bg = B + (size_t)(n0 + srow) * K + scol;
  const int lo = (w << 9);

#define STAGE256(buf, k0)                                             \
  do {                                                                \
    gload_lds16(Ag + (k0), &As[(buf) * 8192 + lo]);                   \
    gload_lds16(Ag + (size_t)128 * K + (k0), &As[(buf) * 8192 + 4096 + lo]); \
    gload_lds16(Bg + (k0), &Bs[(buf) * 4096 + lo]);                   \
  } while (0)

  const int nt = K >> 5;
  STAGE256(0, 0);
  for (int tt = 0; tt < nt; ++tt) {
    const int cb = tt & 1;
    if (tt + 1 < nt) {
      STAGE256(cb ^ 1, (tt + 1) << 5);
      asm volatile("s_waitcnt vmcnt(3)" ::: "memory");
    } else {
      asm volatile("s_waitcnt vmcnt(0)" ::: "memory");
    }
    __builtin_amdgcn_s_barrier();
    __builtin_amdgcn_sched_barrier(0);
    {
      const unsigned short* Ab = &As[cb * 8192];
      const unsigned short* Bb = &Bs[cb * 4096];
      bf16x8 af[4], bfr[4];
#pragma unroll
      for (int fi = 0; fi < 4; ++fi)
        af[fi] = *(const bf16x8*)&Ab[(wr * 64 + fi * 16 + lr) * 32 + koff];
#pragma unroll
      for (int fj = 0; fj < 4; ++fj)
        bfr[fj] = *(const bf16x8*)&Bb[(wc * 64 + fj * 16 + lr) * 32 + koff];
#pragma unroll
      for (int fi = 0; fi < 4; ++fi)
#pragma unroll
        for (int fj = 0; fj < 4; ++fj)
          acc[fi][fj] = __builtin_amdgcn_mfma_f32_16x16x32_bf16(
              bfr[fj], af[fi], acc[fi][fj], 0, 0, 0);
    }
    __builtin_amdgcn_sched_barrier(0);
    __builtin_amdgcn_s_barrier();
  }

  const int mloc = l & 15, ng = (l >> 4) * 4;
#pragma unroll
  for (int fi = 0; fi < 4; ++fi) {
    const int i = i0 + wr * 64 + fi * 16 + mloc;
    const size_t rowbase = (size_t)i * ldc;
#pragma unroll
    for (int fj = 0; fj < 4; ++fj) {
      const int nb = n0 + wc * 64 + fj * 16 + ng;
      *(float4*)((float*)Cout + rowbase + nb) =
          make_float4(acc[fi][fj][0], acc[fi][fj][1], acc[fi][fj][2], acc[fi][fj][3]);
    }
  }
#undef STAGE256
}

// ---------------------------------------------------------------------------
// bf16 MFMA NT GEMM, 64x64 tile, BK=64, 4 waves (per-layer GEMMs).
// B read DIRECTLY from f32 weights: reg-staged (4x float4 issued early),
// converted (HW RNE) and ds_write'd into the SAME bf16 LDS layout after the
// compute phase (T14 issue-early/write-late). A staged via gload_lds16.
// 2-buffer 1-ahead; vmcnt(0)+lgkmcnt(0) before each barrier. Compute phase
// identical to the proven r13 kernel. Optional fused QKV repack epilogue.
// ---------------------------------------------------------------------------
__global__ __launch_bounds__(256) void gemm64_bf16_kernel(
    const unsigned short* __restrict__ A, const float* __restrict__ B32,
    const float* __restrict__ bias, const float* __restrict__ res,
    void* __restrict__ Cout, int M, int N, int K, int ldc, int act, int outbf,
    const int* __restrict__ ntt, unsigned short* __restrict__ Kg,
    unsigned short* __restrict__ Vgt, unsigned short* __restrict__ Vlt) {
  __shared__ __align__(16) unsigned short As[2 * 4096];
  __shared__ __align__(16) unsigned short Bs[2 * 4096];
  const int t = threadIdx.x;
  const int w = t >> 6, l = t & 63;
  const int n0 = blockIdx.x * 64, i0 = blockIdx.y * 64;
  const int wr = w >> 1, wc = w & 1;
  const int lr = l & 15;
  const int koff = (l >> 4) * 8;
  const int T = Kg ? (ntt[0] + 1) : 1;

  f32x4 acc[2][2] = {};

  // A staging (async global->LDS), unchanged layout
  const int srow = t >> 2;
  const int scol = (t & 3) * 8;
  const unsigned short* Ag = A + (size_t)(i0 + srow) * K + scol;
  const int lo0 = (w << 9);
  const int lo1 = 2048 + (w << 9);

  // B reg staging: wave w covers rows [w*16, w*16+16); lane l: row
  // w*16 + (l>>2), 16 consecutive f32 cols from (l&3)*16. Written as two
  // bf16x8 chunks into layout Bs[kk*2048 + row*32 + (col&31)].
  const int brow = w * 16 + (l >> 2);
  const int bc0 = (l & 3) * 16;
  const float* Bg32 = B32 + (size_t)(n0 + brow) * K + bc0;
  const int boff0 = (((bc0 + 0) >> 5) << 11) + brow * 32 + ((bc0 + 0) & 31);
  const int boff1 = (((bc0 + 8) >> 5) << 11) + brow * 32 + ((bc0 + 8) & 31);

#define LOADB(k0)                                  \
  br0 = *(const f32x4*)(Bg32 + (k0));              \
  br1 = *(const f32x4*)(Bg32 + (k0) + 4);          \
  br2 = *(const f32x4*)(Bg32 + (k0) + 8);          \
  br3 = *(const f32x4*)(Bg32 + (k0) + 12);

#define WRITEB(buf)                                                  \
  do {                                                               \
    bf16x8 v0, v1;                                                   \
    v0[0]=(__bf16)br0[0]; v0[1]=(__bf16)br0[1]; v0[2]=(__bf16)br0[2];\
    v0[3]=(__bf16)br0[3]; v0[4]=(__bf16)br1[0]; v0[5]=(__bf16)br1[1];\
    v0[6]=(__bf16)br1[2]; v0[7]=(__bf16)br1[3];                      \
    v1[0]=(__bf16)br2[0]; v1[1]=(__bf16)br2[1]; v1[2]=(__bf16)br2[2];\
    v1[3]=(__bf16)br2[3]; v1[4]=(__bf16)br3[0]; v1[5]=(__bf16)br3[1];\
    v1[6]=(__bf16)br3[2]; v1[7]=(__bf16)br3[3];                      \
    *(bf16x8*)&Bs[(buf) * 4096 + boff0] = v0;                        \
    *(bf16x8*)&Bs[(buf) * 4096 + boff1] = v1;                        \
  } while (0)

#define STAGE_A(buf, k0)                                  \
  do {                                                    \
    gload_lds16(Ag + (k0), &As[(buf) * 4096 + lo0]);      \
    gload_lds16(Ag + (k0) + 32, &As[(buf) * 4096 + lo1]); \
  } while (0)

#define COMPUTE64(buf)                                                        \
  do {                                                                        \
    const unsigned short* Ab = &As[(buf) * 4096];                             \
    const unsigned short* Bb = &Bs[(buf) * 4096];                             \
    bf16x8 af[2][2], bfr[2][2];                                               \
    _Pragma("unroll") for (int fi = 0; fi < 2; ++fi)                          \
      _Pragma("unroll") for (int kk = 0; kk < 2; ++kk)                        \
          af[fi][kk] = *(const bf16x8*)&Ab[kk * 2048 + (wr * 32 + fi * 16 + lr) * 32 + koff]; \
    _Pragma("unroll") for (int fj = 0; fj < 2; ++fj)                          \
      _Pragma("unroll") for (int kk = 0; kk < 2; ++kk)                        \
          bfr[fj][kk] = *(const bf16x8*)&Bb[kk * 2048 + (wc * 32 + fj * 16 + lr) * 32 + koff]; \
    _Pragma("unroll") for (int fi = 0; fi < 2; ++fi)                          \
      _Pragma("unroll") for (int fj = 0; fj < 2; ++fj)                        \
        _Pragma("unroll") for (int kk = 0; kk < 2; ++kk)                      \
            acc[fi][fj] = __builtin_amdgcn_mfma_f32_16x16x32_bf16(            \
                bfr[fj][kk], af[fi][kk], acc[fi][fj], 0, 0, 0);               \
  } while (0)

  f32x4 br0, br1, br2, br3;
  const int nt = K >> 6;

  // prologue: stage tile 0 completely
  LOADB(0);
  STAGE_A(0, 0);
  WRITEB(0);  // compiler waits the br loads before the converts
  asm volatile("s_waitcnt vmcnt(0) lgkmcnt(0)" ::: "memory");
  __builtin_amdgcn_s_barrier();

  for (int tt = 0; tt < nt; ++tt) {
    const int cur = tt & 1;
    if (tt + 1 < nt) {
      LOADB((tt + 1) << 6);
      STAGE_A(cur ^ 1, (tt + 1) << 6);
    }
    __builtin_amdgcn_sched_barrier(0);
    COMPUTE64(cur);
    __builtin_amdgcn_sched_barrier(0);
    if (tt + 1 < nt) {
      WRITEB(cur ^ 1);  // conversion+write lands after compute; loads had
                        // the whole compute phase to return
    }
    asm volatile("s_waitcnt vmcnt(0) lgkmcnt(0)" ::: "memory");
    __builtin_amdgcn_s_barrier();
  }

  const int mloc = l & 15, ng = (l >> 4) * 4;
#pragma unroll
  for (int fi = 0; fi < 2; ++fi) {
    const int i = i0 + wr * 32 + fi * 16 + mloc;
    const size_t rowbase = (size_t)i * ldc;
#pragma unroll
    for (int fj = 0; fj < 2; ++fj) {
      const int nb = n0 + wc * 32 + fj * 16 + ng;
      float z0 = acc[fi][fj][0], z1 = acc[fi][fj][1];
      float z2 = acc[fi][fj][2], z3 = acc[fi][fj][3];
      if (bias) {
        float4 bv = *(const float4*)(bias + nb);
        z0 += bv.x; z1 += bv.y; z2 += bv.z; z3 += bv.w;
      }
      if (act) {
        z0 = gelu_exact(z0); z1 = gelu_exact(z1);
        z2 = gelu_exact(z2); z3 = gelu_exact(z3);
      }
      if (res) {
        float4 rv = *(const float4*)(res + rowbase + nb);
        z0 += rv.x; z1 += rv.y; z2 += rv.z; z3 += rv.w;
      }
      if (outbf) {
        u16x4 o;
        o[0] = f2bf(z0); o[1] = f2bf(z1); o[2] = f2bf(z2); o[3] = f2bf(z3);
        *(u16x4*)((unsigned short*)Cout + rowbase + nb) = o;
        if (Kg) {
          if (nb >= DMODEL && nb < 2 * DMODEL) {
            if (i % T == 0) {
              const int gg = i / T;
              if (gg < MAXLEN_C) {
                const int kcol = nb - DMODEL;
                const int h = kcol / HDIM, d = kcol - h * HDIM;
                *(u16x4*)&Kg[((size_t)h * 512 + gg) * HDIM + d] = o;
              }
            }
          } else if (nb >= 2 * DMODEL) {
            const int vcol = nb - 2 * DMODEL;
            const int h = vcol / HDIM, d = vcol - h * HDIM;
            Vlt[((size_t)h * HDIM + d + 0) * VLT_LD + i] = o[0];
            Vlt[((size_t)h * HDIM + d + 1) * VLT_LD + i] = o[1];
            Vlt[((size_t)h * HDIM + d + 2) * VLT_LD + i] = o[2];
            Vlt[((size_t)h * HDIM + d + 3) * VLT_LD + i] = o[3];
            if (i % T == 0) {
              const int gg = i / T;
              if (gg < MAXLEN_C) {
                Vgt[((size_t)h * HDIM + d + 0) * 512 + gg] = o[0];
                Vgt[((size_t)h * HDIM + d + 1) * 512 + gg] = o[1];
                Vgt[((size_t)h * HDIM + d + 2) * 512 + gg] = o[2];
                Vgt[((size_t)h * HDIM + d + 3) * 512 + gg] = o[3];
              }
            }
          }
        }
      } else {
        *(float4*)((float*)Cout + rowbase + nb) = make_float4(z0, z1, z2, z3);
      }
    }
  }
#undef LOADB
#undef WRITEB
#undef STAGE_A
#undef COMPUTE64
}

// ---------------------------------------------------------------------------
// MFMA flash attention over the block-causal mask. setprio(1) around MFMA
// clusters (T5: 4 independent-phase waves per block -> m191 regime).
// ---------------------------------------------------------------------------
__global__ __launch_bounds__(256) void attn_flash_kernel(
    const unsigned short* __restrict__ qkv, const unsigned short* __restrict__ Kg,
    const unsigned short* __restrict__ Vgt, const unsigned short* __restrict__ Vlt,
    const int* __restrict__ ntt, unsigned short* __restrict__ att) {
  __shared__ float Osh[4][96][17];
  __shared__ float Msh[4][16];
  __shared__ float Lsh[4][16];
  const int s = blockIdx.x, h = blockIdx.y;
  const int T = ntt[0] + 1;
  const int tid = threadIdx.x;
  const int w = tid >> 6, l = tid & 63;
  const int q15 = l & 15, grp = l >> 4;
  const int p0 = s * 16;
  const int p = p0 + q15;
  const int myTok = p / T;

  const unsigned short* qrow = qkv + (size_t)p * QKVD + h * HDIM + grp * 8;
  bf16x8 qf0 = *(const bf16x8*)(qrow);
  bf16x8 qf1 = *(const bf16x8*)(qrow + 32);
  bf16x8 qf2 = *(const bf16x8*)(qrow + 64);

  float m_run = M_INIT, l_run = 0.0f;
  f32x4 oacc[6] = {};

  const int gmax = (p0 + 15) / T;
  const int KP = (gmax >> 5) + 1;
  const unsigned short* KgH = Kg + (size_t)h * 512 * 96;
  const unsigned short* VgH = Vgt + (size_t)h * 96 * 512;

  for (int kp = w; kp < KP; kp += 4) {
    f32x4 s0 = {}, s1 = {};
    const unsigned short* k0r = KgH + (size_t)(kp * 32 + q15) * 96 + grp * 8;
    const unsigned short* k1r = k0r + 16 * 96;
    {
      bf16x8 a0 = *(const bf16x8*)(k0r);
      bf16x8 a1 = *(const bf16x8*)(k1r);
      bf16x8 b0 = *(const bf16x8*)(k0r + 32);
      bf16x8 b1 = *(const bf16x8*)(k1r + 32);
      bf16x8 c0 = *(const bf16x8*)(k0r + 64);
      bf16x8 c1 = *(const bf16x8*)(k1r + 64);
      __builtin_amdgcn_s_setprio(1);
      s0 = __builtin_amdgcn_mfma_f32_16x16x32_bf16(a0, qf0, s0, 0, 0, 0);
      s1 = __builtin_amdgcn_mfma_f32_16x16x32_bf16(a1, qf0, s1, 0, 0, 0);
      s0 = __builtin_amdgcn_mfma_f32_16x16x32_bf16(b0, qf1, s0, 0, 0, 0);
      s1 = __builtin_amdgcn_mfma_f32_16x16x32_bf16(b1, qf1, s1, 0, 0, 0);
      s0 = __builtin_amdgcn_mfma_f32_16x16x32_bf16(c0, qf2, s0, 0, 0, 0);
      s1 = __builtin_amdgcn_mfma_f32_16x16x32_bf16(c1, qf2, s1, 0, 0, 0);
      __builtin_amdgcn_s_setprio(0);
    }
    float sc[8];
#pragma unroll
    for (int e = 0; e < 4; ++e) {
      int g = kp * 32 + grp * 4 + e;
      sc[e] = (g * T <= p) ? s0[e] * QK_SCALE : NEG_BIG;
      g += 16;
      sc[4 + e] = (g * T <= p) ? s1[e] * QK_SCALE : NEG_BIG;
    }
    float tmax = sc[0];
#pragma unroll
    for (int e = 1; e < 8; ++e) tmax = fmaxf(tmax, sc[e]);
    tmax = fmaxf(tmax, __shfl_xor(tmax, 16));
    tmax = fmaxf(tmax, __shfl_xor(tmax, 32));
    float mnew = fmaxf(m_run, tmax);
    float alpha = __expf(m_run - mnew);
    float pv[8], ps = 0.0f;
#pragma unroll
    for (int e = 0; e < 8; ++e) { pv[e] = __expf(sc[e] - mnew); ps += pv[e]; }
    ps += __shfl_xor(ps, 16);
    ps += __shfl_xor(ps, 32);
    l_run = l_run * alpha + ps;
    m_run = mnew;
#pragma unroll
    for (int dt = 0; dt < 6; ++dt) oacc[dt] *= alpha;
    unsigned int pk0[2], pk1[2];
    pk0[0] = pack2bf(pv[0], pv[1]); pk0[1] = pack2bf(pv[2], pv[3]);
    pk1[0] = pack2bf(pv[4], pv[5]); pk1[1] = pack2bf(pv[6], pv[7]);
    union { unsigned int u[4]; bf16x8 v; } pf;
#pragma unroll
    for (int w2 = 0; w2 < 4; ++w2) {
      int src = (((grp & 1) << 1) + (w2 >> 1)) * 16 + q15;
      int y0 = __shfl((int)pk0[w2 & 1], src);
      int y1 = __shfl((int)pk1[w2 & 1], src);
      pf.u[w2] = (grp >> 1) ? (unsigned int)y1 : (unsigned int)y0;
    }
    __builtin_amdgcn_s_setprio(1);
#pragma unroll
    for (int dt = 0; dt < 6; ++dt) {
      bf16x8 vf = *(const bf16x8*)(VgH + (size_t)(dt * 16 + q15) * 512 + kp * 32 + grp * 8);
      oacc[dt] = __builtin_amdgcn_mfma_f32_16x16x32_bf16(vf, pf.v, oacc[dt], 0, 0, 0);
    }
    __builtin_amdgcn_s_setprio(0);
  }

  if (w == 3) {
    f32x4 s0 = {};
    const unsigned short* kl = qkv + (size_t)(p0 + q15) * QKVD + DMODEL + h * HDIM + grp * 8;
    __builtin_amdgcn_s_setprio(1);
    s0 = __builtin_amdgcn_mfma_f32_16x16x32_bf16(*(const bf16x8*)(kl), qf0, s0, 0, 0, 0);
    s0 = __builtin_amdgcn_mfma_f32_16x16x32_bf16(*(const bf16x8*)(kl + 32), qf1, s0, 0, 0, 0);
    s0 = __builtin_amdgcn_mfma_f32_16x16x32_bf16(*(const bf16x8*)(kl + 64), qf2, s0, 0, 0, 0);
    __builtin_amdgcn_s_setprio(0);
    float sc[4];
#pragma unroll
    for (int e = 0; e < 4; ++e) {
      int pk = p0 + grp * 4 + e;
      bool ok = (pk / T == myTok) && (pk % T != 0) && (pk <= p);
      sc[e] = ok ? s0[e] * QK_SCALE : NEG_BIG;
    }
    float tmax = fmaxf(fmaxf(sc[0], sc[1]), fmaxf(sc[2], sc[3]));
    tmax = fmaxf(tmax, __shfl_xor(tmax, 16));
    tmax = fmaxf(tmax, __shfl_xor(tmax, 32));
    float mnew = fmaxf(m_run, tmax);
    float alpha = __expf(m_run - mnew);
    float pv[4], ps = 0.0f;
#pragma unroll
    for (int e = 0; e < 4; ++e) { pv[e] = __expf(sc[e] - mnew); ps += pv[e]; }
    ps += __shfl_xor(ps, 16);
    ps += __shfl_xor(ps, 32);
    l_run = l_run * alpha + ps;
    m_run = mnew;
#pragma unroll
    for (int dt = 0; dt < 6; ++dt) oacc[dt] *= alpha;
    unsigned int pk0[2];
    pk0[0] = pack2bf(pv[0], pv[1]); pk0[1] = pack2bf(pv[2], pv[3]);
    union { unsigned int u[4]; bf16x8 v; } pf;
#pragma unroll
    for (int w2 = 0; w2 < 4; ++w2) {
      int src = (((grp & 1) << 1) + (w2 >> 1)) * 16 + q15;
      int y0 = __shfl((int)pk0[w2 & 1], src);
      pf.u[w2] = (grp >> 1) ? 0u : (unsigned int)y0;
    }
    __builtin_amdgcn_s_setprio(1);
#pragma unroll
    for (int dt = 0; dt < 6; ++dt) {
      bf16x8 vf = *(const bf16x8*)(Vlt + ((size_t)h * 96 + dt * 16 + q15) * VLT_LD + p0 + grp * 8);
      oacc[dt] = __builtin_amdgcn_mfma_f32_16x16x32_bf16(vf, pf.v, oacc[dt], 0, 0, 0);
    }
    __builtin_amdgcn_s_setprio(0);
  }

  if (l < 16) { Msh[w][l] = m_run; Lsh[w][l] = l_run; }
#pragma unroll
  for (int dt = 0; dt < 6; ++dt)
#pragma unroll
    for (int e = 0; e < 4; ++e)
      Osh[w][dt * 16 + grp * 4 + e][q15] = oacc[dt][e];
  __syncthreads();

  {
    const int q = tid & 15, dg = tid >> 4;
    float m0 = Msh[0][q], m1 = Msh[1][q], m2 = Msh[2][q], m3 = Msh[3][q];
    float ms = fmaxf(fmaxf(m0, m1), fmaxf(m2, m3));
    float c0 = __expf(m0 - ms), c1 = __expf(m1 - ms);
    float c2 = __expf(m2 - ms), c3 = __expf(m3 - ms);
    float lsum = c0 * Lsh[0][q] + c1 * Lsh[1][q] + c2 * Lsh[2][q] + c3 * Lsh[3][q];
    float rinv = 1.0f / lsum;
    unsigned short* orow = att + (size_t)(p0 + q) * DMODEL + h * HDIM;
#pragma unroll
    for (int j = 0; j < 6; ++j) {
      int d = dg * 6 + j;
      float o = c0 * Osh[0][d][q] + c1 * Osh[1][d][q] +
                c2 * Osh[2][d][q] + c3 * Osh[3][d][q];
      orow[d] = f2bf(o * rinv);
    }
  }
}

// ---------------------------------------------------------------------------
// Value head stage 2: values[i] = sum_f F1[i][f] * w2[f] + b2[0]  (F1 bf16)
// ---------------------------------------------------------------------------
__global__ __launch_bounds__(256) void v2_kernel(
    const unsigned short* __restrict__ F1, const float* __restrict__ w2,
    const float* __restrict__ b2, float* __restrict__ out) {
  __shared__ float red[4];
  const int row = blockIdx.x;
  const int tid = threadIdx.x;
  float s = 0.0f;
  const unsigned short* xr = F1 + (size_t)row * FFDIM;
  for (int f = tid; f < FFDIM; f += 256) s += bf2f(xr[f]) * w2[f];
  for (int o = 32; o; o >>= 1) s += __shfl_xor(s, o);
  if ((tid & 63) == 0) red[tid >> 6] = s;
  __syncthreads();
  if (tid == 0) out[row] = red[0] + red[1] + red[2] + red[3] + b2[0];
}

// ---------------------------------------------------------------------------
extern "C" void kernel_launch(void* const* d_in, const int* in_sizes, int n_in,
                              void* d_out, int out_size, void* d_ws, size_t ws_size,
                              hipStream_t stream) {
  const float* se      = (const float*)d_in[0];
  const float* pe      = (const float*)d_in[2];
  const float* th      = (const float*)d_in[3];
  const float* w_qkv   = (const float*)d_in[4];
  const float* b_qkv   = (const float*)d_in[5];
  const float* w_out   = (const float*)d_in[6];
  const float* b_out   = (const float*)d_in[7];
  const float* ln1_g   = (const float*)d_in[8];
  const float* ln1_b   = (const float*)d_in[9];
  const float* ln2_g   = (const float*)d_in[10];
  const float* ln2_b   = (const float*)d_in[11];
  const float* w_ff1   = (const float*)d_in[12];
  const float* b_ff1   = (const float*)d_in[13];
  const float* w_ff2   = (const float*)d_in[14];
  const float* b_ff2   = (const float*)d_in[15];
  const float* fn_g    = (const float*)d_in[16];
  const float* fn_b    = (const float*)d_in[17];
  const float* w_pol   = (const float*)d_in[18];
  const float* w_v1    = (const float*)d_in[19];
  const float* b_v1    = (const float*)d_in[20];
  const float* w_v2    = (const float*)d_in[21];
  const float* b_v2    = (const float*)d_in[22];
  const int*   ntt     = (const int*)d_in[23];

  float* logits = (float*)d_out;
  float* values = logits + (size_t)S_TOT * VOCAB;

  const int nq = 3 * DMODEL * DMODEL, no = DMODEL * DMODEL;
  const int nf1 = FFDIM * DMODEL, nf2 = DMODEL * FFDIM;
  const int npol = VOCAB * DMODEL;

  // activations layout
  char* p = (char*)d_ws;
  float* X             = (float*)p;          p += (size_t)S_TOT * DMODEL * 4;
  unsigned short* Ybf  = (unsigned short*)p; p += (size_t)S_TOT * DMODEL * 2;
  unsigned short* QKVb = (unsigned short*)p; p += (size_t)S_TOT * QKVD * 2;
  unsigned short* ATTb = (unsigned short*)p; p += (size_t)S_TOT * DMODEL * 2;
  unsigned short* F1b  = (unsigned short*)p; p += (size_t)S_TOT * FFDIM * 2;
  unsigned short* Kg   = (unsigned short*)p; p += (size_t)NHEAD * 512 * 96 * 2;
  unsigned short* Vgt  = (unsigned short*)p; p += (size_t)NHEAD * 96 * 512 * 2;
  unsigned short* Vlt  = (unsigned short*)p; p += (size_t)NHEAD * 96 * VLT_LD * 2;

  // bf16 policy weights (big-ws: whole matrix; fallback: POL_CHUNK buffer)
  const size_t used = (size_t)(p - (char*)d_ws);
  const bool bigws = ws_size >= used + (size_t)npol * 2 + (1u << 20);
  unsigned short* WpolA = (unsigned short*)p;

  dim3 blk(256);

  if (bigws) {
    cvt_kernel<<<dim3((npol / 4 + 255) / 256), blk, 0, stream>>>(w_pol, WpolA, npol);
  }

  embed_kernel<<<dim3((S_TOT * DMODEL + 255) / 256), blk, 0, stream>>>(se, pe, th, ntt, X);

  for (int l = 0; l < 8; ++l) {
    const float* pWq  = w_qkv + (size_t)l * nq;
    const float* pWo  = w_out + (size_t)l * no;
    const float* pWf1 = w_ff1 + (size_t)l * nf1;
    const float* pWf2 = w_ff2 + (size_t)l * nf2;

    ln_bf_kernel<<<dim3(S_TOT), blk, 0, stream>>>(X, ln1_g + l * DMODEL, ln1_b + l * DMODEL, Ybf);
    // QKV GEMM: f32 weights direct + fused K/V repack
    gemm64_bf16_kernel<<<dim3(QKVD / 64, S_TOT / 64), blk, 0, stream>>>(
        Ybf, pWq, b_qkv + (size_t)l * 3 * DMODEL, nullptr, QKVb,
        S_TOT, QKVD, DMODEL, QKVD, 0, 1, ntt, Kg, Vgt, Vlt);
    attn_flash_kernel<<<dim3(S_TOT / 16, NHEAD), blk, 0, stream>>>(
        QKVb, Kg, Vgt, Vlt, ntt, ATTb);
    gemm64_bf16_kernel<<<dim3(DMODEL / 64, S_TOT / 64), blk, 0, stream>>>(
        ATTb, pWo, b_out + (size_t)l * DMODEL, X, X,
        S_TOT, DMODEL, DMODEL, DMODEL, 0, 0, nullptr, nullptr, nullptr, nullptr);

    ln_bf_kernel<<<dim3(S_TOT), blk, 0, stream>>>(X, ln2_g + l * DMODEL, ln2_b + l * DMODEL, Ybf);
    gemm64_bf16_kernel<<<dim3(FFDIM / 64, S_TOT / 64), blk, 0, stream>>>(
        Ybf, pWf1, b_ff1 + (size_t)l * FFDIM, nullptr, F1b,
        S_TOT, FFDIM, DMODEL, FFDIM, 1, 1, nullptr, nullptr, nullptr, nullptr);
    gemm64_bf16_kernel<<<dim3(DMODEL / 64, S_TOT / 64), blk, 0, stream>>>(
        F1b, pWf2, b_ff2 + (size_t)l * DMODEL, X, X,
        S_TOT, DMODEL, FFDIM, DMODEL, 0, 0, nullptr, nullptr, nullptr, nullptr);
  }

  ln_bf_kernel<<<dim3(S_TOT), blk, 0, stream>>>(X, fn_g, fn_b, Ybf);

  if (bigws) {
    // policy head: 256x128 tile, 8 waves, 2000 blocks, m-fastest XCD swizzle
    gemm256_bf16_kernel<<<dim3((S_TOT / 256) * (VOCAB / 128)), dim3(512), 0, stream>>>(
        Ybf, WpolA, logits, S_TOT, VOCAB, DMODEL, VOCAB);
  } else {
    for (int c = 0; c < VOCAB / POL_CHUNK; ++c) {
      cvt_kernel<<<dim3((POL_CHUNK * DMODEL / 4 + 255) / 256), blk, 0, stream>>>(
          w_pol + (size_t)c * POL_CHUNK * DMODEL, WpolA, POL_CHUNK * DMODEL);
      gemm_bf16_kernel<<<dim3(POL_CHUNK / 128, S_TOT / 128), blk, 0, stream>>>(
          Ybf, WpolA, nullptr, nullptr, logits + (size_t)c * POL_CHUNK,
          S_TOT, POL_CHUNK, DMODEL, VOCAB, 0, 0, 0);
    }
  }

  // value head: f32 weights direct
  gemm64_bf16_kernel<<<dim3(FFDIM / 64, S_TOT / 64), blk, 0, stream>>>(
      Ybf, w_v1, b_v1, nullptr, F1b, S_TOT, FFDIM, DMODEL, FFDIM, 1, 1,
      nullptr, nullptr, nullptr, nullptr);
  v2_kernel<<<dim3(S_TOT), blk, 0, stream>>>(F1b, w_v2, b_v2, values);
}

// Round 15
// 1291.404 us; speedup vs baseline: 1.0604x; 1.0604x over previous
//
#include <hip/hip_runtime.h>
#include <math.h>

#define S_TOT 2048
#define DMODEL 768
#define QKVD 2304
#define NHEAD 8
#define HDIM 96
#define FFDIM 2048
#define VOCAB 32000
#define MAXLEN_C 512
#define POL_CHUNK 3200   // fallback path only
#define VLT_LD 2080      // 2048 + 32 pad so k-frag overreads stay in-bounds
#define NEG_BIG (-3.0e38f)
#define M_INIT (-1.0e30f)
#define QK_SCALE 0.10206207261596575f  // 1/sqrt(96)

typedef __bf16 bf16x8 __attribute__((ext_vector_type(8)));
typedef float f32x4 __attribute__((ext_vector_type(4)));
typedef unsigned short u16x8 __attribute__((ext_vector_type(8)));
typedef unsigned short u16x4 __attribute__((ext_vector_type(4)));

__device__ __forceinline__ float gelu_exact(float x) {
  return 0.5f * x * (1.0f + erff(x * 0.70710678118654752f));
}

__device__ __forceinline__ float bf2f(unsigned short u) {
  union { unsigned int i; float f; } v;
  v.i = ((unsigned int)u) << 16;
  return v.f;
}

__device__ __forceinline__ unsigned short f2bf(float f) {
  union { float f; unsigned int i; } v;
  v.f = f;
  unsigned int x = v.i;
  return (unsigned short)((x + 0x7fffu + ((x >> 16) & 1u)) >> 16);  // RNE
}

__device__ __forceinline__ unsigned int pack2bf(float a, float b) {
  return (unsigned int)f2bf(a) | ((unsigned int)f2bf(b) << 16);
}

// async global->LDS, 16B per lane; dst must be wave-uniform base
__device__ __forceinline__ void gload_lds16(const unsigned short* g, unsigned short* l) {
  __builtin_amdgcn_global_load_lds(
      (const __attribute__((address_space(1))) unsigned int*)g,
      (__attribute__((address_space(3))) unsigned int*)l, 16, 0, 0);
}

// ---------------------------------------------------------------------------
// Embed: x[p] = se[p] + pe[p/T] + th[p%T] for p < MAXLEN*T, else 0 (f32 out)
// ---------------------------------------------------------------------------
__global__ __launch_bounds__(256) void embed_kernel(
    const float* __restrict__ se, const float* __restrict__ pe,
    const float* __restrict__ th, const int* __restrict__ ntt,
    float* __restrict__ X) {
  int idx = blockIdx.x * 256 + threadIdx.x;
  if (idx >= S_TOT * DMODEL) return;
  int p = idx / DMODEL;
  int d = idx - p * DMODEL;
  int T = ntt[0] + 1;
  float v = 0.0f;
  if (p < MAXLEN_C * T) {
    v = se[idx] + pe[(p / T) * DMODEL + d] + th[(p % T) * DMODEL + d];
  }
  X[idx] = v;
}

// ---------------------------------------------------------------------------
// LayerNorm f32 in -> bf16 out. One block (256 thr) per row, 3 elems/thread.
// ---------------------------------------------------------------------------
__global__ __launch_bounds__(256) void ln_bf_kernel(
    const float* __restrict__ X, const float* __restrict__ g,
    const float* __restrict__ b, unsigned short* __restrict__ Y) {
  __shared__ float red[4];
  const int row = blockIdx.x;
  const int tid = threadIdx.x;
  const float* x = X + (size_t)row * DMODEL;
  float v0 = x[tid], v1 = x[tid + 256], v2 = x[tid + 512];
  float s = v0 + v1 + v2;
  for (int o = 32; o; o >>= 1) s += __shfl_xor(s, o);
  if ((tid & 63) == 0) red[tid >> 6] = s;
  __syncthreads();
  float mean = (red[0] + red[1] + red[2] + red[3]) * (1.0f / DMODEL);
  float d0 = v0 - mean, d1 = v1 - mean, d2 = v2 - mean;
  float s2 = d0 * d0 + d1 * d1 + d2 * d2;
  for (int o = 32; o; o >>= 1) s2 += __shfl_xor(s2, o);
  __syncthreads();
  if ((tid & 63) == 0) red[tid >> 6] = s2;
  __syncthreads();
  float var = (red[0] + red[1] + red[2] + red[3]) * (1.0f / DMODEL);
  float rstd = rsqrtf(var + 1e-4f);
  unsigned short* y = Y + (size_t)row * DMODEL;
  y[tid]       = f2bf(d0 * rstd * g[tid]       + b[tid]);
  y[tid + 256] = f2bf(d1 * rstd * g[tid + 256] + b[tid + 256]);
  y[tid + 512] = f2bf(d2 * rstd * g[tid + 512] + b[tid + 512]);
}

// ---------------------------------------------------------------------------
// f32 -> bf16 convert, n divisible by 4
// ---------------------------------------------------------------------------
__global__ __launch_bounds__(256) void cvt_kernel(
    const float* __restrict__ s, unsigned short* __restrict__ d, int n) {
  int i = (blockIdx.x * 256 + threadIdx.x) * 4;
  if (i >= n) return;
  float4 v = *(const float4*)(s + i);
  u16x4 o;
  o[0] = f2bf(v.x); o[1] = f2bf(v.y); o[2] = f2bf(v.z); o[3] = f2bf(v.w);
  *(u16x4*)(d + i) = o;
}

// fused 4-array convert (fallback per-layer path)
__global__ __launch_bounds__(256) void cvt4_kernel(
    const float* __restrict__ s0, const float* __restrict__ s1,
    const float* __restrict__ s2, const float* __restrict__ s3,
    unsigned short* __restrict__ d0, unsigned short* __restrict__ d1,
    unsigned short* __restrict__ d2, unsigned short* __restrict__ d3,
    int n0, int n1, int n2, int n3) {
  int i = (blockIdx.x * 256 + threadIdx.x) * 4;
  const float* s;
  unsigned short* d;
  if (i < n0) { s = s0; d = d0; }
  else if (i < n0 + n1) { i -= n0; s = s1; d = d1; }
  else if (i < n0 + n1 + n2) { i -= n0 + n1; s = s2; d = d2; }
  else if (i < n0 + n1 + n2 + n3) { i -= n0 + n1 + n2; s = s3; d = d3; }
  else return;
  float4 v = *(const float4*)(s + i);
  u16x4 o;
  o[0] = f2bf(v.x); o[1] = f2bf(v.y); o[2] = f2bf(v.z); o[3] = f2bf(v.w);
  *(u16x4*)(d + i) = o;
}

// one-shot 6-region convert (all weights, big-ws path)
__global__ __launch_bounds__(256) void cvt6_kernel(
    const float* __restrict__ s0, const float* __restrict__ s1,
    const float* __restrict__ s2, const float* __restrict__ s3,
    const float* __restrict__ s4, const float* __restrict__ s5,
    unsigned short* __restrict__ d0, unsigned short* __restrict__ d1,
    unsigned short* __restrict__ d2, unsigned short* __restrict__ d3,
    unsigned short* __restrict__ d4, unsigned short* __restrict__ d5,
    int n0, int n1, int n2, int n3, int n4, int n5) {
  int i = (blockIdx.x * 256 + threadIdx.x) * 4;
  const float* s;
  unsigned short* d;
  if (i < n0) { s = s0; d = d0; }
  else if (i < n0 + n1) { i -= n0; s = s1; d = d1; }
  else if (i < n0 + n1 + n2) { i -= n0 + n1; s = s2; d = d2; }
  else if (i < n0 + n1 + n2 + n3) { i -= n0 + n1 + n2; s = s3; d = d3; }
  else if (i < n0 + n1 + n2 + n3 + n4) { i -= n0 + n1 + n2 + n3; s = s4; d = d4; }
  else if (i < n0 + n1 + n2 + n3 + n4 + n5) { i -= n0 + n1 + n2 + n3 + n4; s = s5; d = d5; }
  else return;
  float4 v = *(const float4*)(s + i);
  u16x4 o;
  o[0] = f2bf(v.x); o[1] = f2bf(v.y); o[2] = f2bf(v.z); o[3] = f2bf(v.w);
  *(u16x4*)(d + i) = o;
}

// ---------------------------------------------------------------------------
// bf16 MFMA NT GEMM, 128x128 tile, BK=32, 4 waves (fallback small-ws path).
// ---------------------------------------------------------------------------
__global__ __launch_bounds__(256) void gemm_bf16_kernel(
    const unsigned short* __restrict__ A, const unsigned short* __restrict__ B,
    const float* __restrict__ bias, const float* __restrict__ res,
    void* __restrict__ Cout, int M, int N, int K, int ldc, int act, int outbf,
    int swiz) {
  __shared__ __align__(16) unsigned short As[3 * 4096];
  __shared__ __align__(16) unsigned short Bs[3 * 4096];
  const int t = threadIdx.x;
  const int w = t >> 6, l = t & 63;
  int n_blk, m_blk;
  if (swiz) {
    const int g = blockIdx.x;
    const int chunk = gridDim.x >> 3;
    const int logical = (g & 7) * chunk + (g >> 3);
    m_blk = logical & 15;
    n_blk = logical >> 4;
  } else {
    n_blk = blockIdx.x; m_blk = blockIdx.y;
  }
  const int n0 = n_blk * 128, i0 = m_blk * 128;
  const int wr = w >> 1, wc = w & 1;
  const int lr = l & 15;
  const int koff = (l >> 4) * 8;

  f32x4 acc[4][4] = {};

  const int srow = t >> 2;
  const int scol = (t & 3) * 8;
  const unsigned short* Ag = A + (size_t)(i0 + srow) * K + scol;
  const unsigned short* Bg = B + (size_t)(n0 + srow) * K + scol;
  const int lo0 = (w << 9);
  const int lo1 = 2048 + (w << 9);

#define STAGE128(buf, k0)                                        \
  do {                                                           \
    gload_lds16(Ag + (k0), &As[(buf) * 4096 + lo0]);             \
    gload_lds16(Ag + (size_t)64 * K + (k0), &As[(buf) * 4096 + lo1]); \
    gload_lds16(Bg + (k0), &Bs[(buf) * 4096 + lo0]);             \
    gload_lds16(Bg + (size_t)64 * K + (k0), &Bs[(buf) * 4096 + lo1]); \
  } while (0)

#define COMPUTE128(buf)                                                   \
  do {                                                                    \
    const unsigned short* Ab = &As[(buf) * 4096];                         \
    const unsigned short* Bb = &Bs[(buf) * 4096];                         \
    bf16x8 af[4], bfr[4];                                                 \
    _Pragma("unroll") for (int fi = 0; fi < 4; ++fi)                      \
        af[fi] = *(const bf16x8*)&Ab[(wr * 64 + fi * 16 + lr) * 32 + koff]; \
    _Pragma("unroll") for (int fj = 0; fj < 4; ++fj)                      \
        bfr[fj] = *(const bf16x8*)&Bb[(wc * 64 + fj * 16 + lr) * 32 + koff]; \
    _Pragma("unroll") for (int fi = 0; fi < 4; ++fi)                      \
      _Pragma("unroll") for (int fj = 0; fj < 4; ++fj)                    \
          acc[fi][fj] = __builtin_amdgcn_mfma_f32_16x16x32_bf16(          \
              bfr[fj], af[fi], acc[fi][fj], 0, 0, 0);                     \
  } while (0)

  const int nt = K >> 5;
  STAGE128(0, 0);
  if (nt > 1) STAGE128(1, 32);
  for (int tt = 0; tt < nt; ++tt) {
    __builtin_amdgcn_s_barrier();
    if (tt + 2 < nt) {
      STAGE128((tt + 2) % 3, (tt + 2) << 5);
      asm volatile("s_waitcnt vmcnt(8)" ::: "memory");
    } else if (tt + 1 < nt) {
      asm volatile("s_waitcnt vmcnt(4)" ::: "memory");
    } else {
      asm volatile("s_waitcnt vmcnt(0)" ::: "memory");
    }
    __builtin_amdgcn_sched_barrier(0);
    COMPUTE128(tt % 3);
    __builtin_amdgcn_sched_barrier(0);
  }

  const int mloc = l & 15, ng = (l >> 4) * 4;
#pragma unroll
  for (int fi = 0; fi < 4; ++fi) {
    const int i = i0 + wr * 64 + fi * 16 + mloc;
    const size_t rowbase = (size_t)i * ldc;
#pragma unroll
    for (int fj = 0; fj < 4; ++fj) {
      const int nb = n0 + wc * 64 + fj * 16 + ng;
      float z0 = acc[fi][fj][0], z1 = acc[fi][fj][1];
      float z2 = acc[fi][fj][2], z3 = acc[fi][fj][3];
      if (bias) {
        float4 bv = *(const float4*)(bias + nb);
        z0 += bv.x; z1 += bv.y; z2 += bv.z; z3 += bv.w;
      }
      if (act) {
        z0 = gelu_exact(z0); z1 = gelu_exact(z1);
        z2 = gelu_exact(z2); z3 = gelu_exact(z3);
      }
      if (res) {
        float4 rv = *(const float4*)(res + rowbase + nb);
        z0 += rv.x; z1 += rv.y; z2 += rv.z; z3 += rv.w;
      }
      if (outbf) {
        u16x4 o;
        o[0] = f2bf(z0); o[1] = f2bf(z1); o[2] = f2bf(z2); o[3] = f2bf(z3);
        *(u16x4*)((unsigned short*)Cout + rowbase + nb) = o;
      } else {
        *(float4*)((float*)Cout + rowbase + nb) = make_float4(z0, z1, z2, z3);
      }
    }
  }
#undef STAGE128
#undef COMPUTE128
}

// ---------------------------------------------------------------------------
// bf16 MFMA NT GEMM, 256(M)x128(N) tile, BK=32, 8 waves (512 thr) — the r10
// measured-best policy config: 2-buffer 1-ahead, vmcnt(3), two barriers.
// XCD-chunk swizzle, m-fastest (M/256 == 8).
// ---------------------------------------------------------------------------
__global__ __launch_bounds__(512) void gemm256_bf16_kernel(
    const unsigned short* __restrict__ A, const unsigned short* __restrict__ B,
    void* __restrict__ Cout, int M, int N, int K, int ldc) {
  __shared__ __align__(16) unsigned short As[2 * 8192];  // 256 x 32 per buf
  __shared__ __align__(16) unsigned short Bs[2 * 4096];  // 128 x 32 per buf
  const int t = threadIdx.x;
  const int w = t >> 6, l = t & 63;
  const int g = blockIdx.x;
  const int chunk = gridDim.x >> 3;
  const int logical = (g & 7) * chunk + (g >> 3);
  const int m_blk = logical & 7;    // M/256 == 8
  const int n_blk = logical >> 3;
  const int n0 = n_blk * 128, i0 = m_blk * 256;
  const int wr = w >> 1;            // 0..3 -> 64-row quarter
  const int wc = w & 1;             // 0..1 -> 64-col half
  const int lr = l & 15;
  const int koff = (l >> 4) * 8;

  f32x4 acc[4][4] = {};

  const int srow = t >> 2;          // 0..127
  const int scol = (t & 3) * 8;
  const unsigned short* Ag = A + (size_t)(i0 + srow) * K + scol;
  const unsigned short* Bg = B + (size_t)(n0 + srow) * K + scol;
  const int lo = (w << 9);

#define STAGE256(buf, k0)                                             \
  do {                                                                \
    gload_lds16(Ag + (k0), &As[(buf) * 8192 + lo]);                   \
    gload_lds16(Ag + (size_t)128 * K + (k0), &As[(buf) * 8192 + 4096 + lo]); \
    gload_lds16(Bg + (k0), &Bs[(buf) * 4096 + lo]);                   \
  } while (0)

  const int nt = K >> 5;
  STAGE256(0, 0);
  for (int tt = 0; tt < nt; ++tt) {
    const int cb = tt & 1;
    if (tt + 1 < nt) {
      STAGE256(cb ^ 1, (tt + 1) << 5);
      asm volatile("s_waitcnt vmcnt(3)" ::: "memory");
    } else {
      asm volatile("s_waitcnt vmcnt(0)" ::: "memory");
    }
    __builtin_amdgcn_s_barrier();
    __builtin_amdgcn_sched_barrier(0);
    {
      const unsigned short* Ab = &As[cb * 8192];
      const unsigned short* Bb = &Bs[cb * 4096];
      bf16x8 af[4], bfr[4];
#pragma unroll
      for (int fi = 0; fi < 4; ++fi)
        af[fi] = *(const bf16x8*)&Ab[(wr * 64 + fi * 16 + lr) * 32 + koff];
#pragma unroll
      for (int fj = 0; fj < 4; ++fj)
        bfr[fj] = *(const bf16x8*)&Bb[(wc * 64 + fj * 16 + lr) * 32 + koff];
#pragma unroll
      for (int fi = 0; fi < 4; ++fi)
#pragma unroll
        for (int fj = 0; fj < 4; ++fj)
          acc[fi][fj] = __builtin_amdgcn_mfma_f32_16x16x32_bf16(
              bfr[fj], af[fi], acc[fi][fj], 0, 0, 0);
    }
    __builtin_amdgcn_sched_barrier(0);
    __builtin_amdgcn_s_barrier();
  }

  // epilogue (no bias/act/res; f32 out): lane m = l&15, n = (l>>4)*4+reg
  const int mloc = l & 15, ng = (l >> 4) * 4;
#pragma unroll
  for (int fi = 0; fi < 4; ++fi) {
    const int i = i0 + wr * 64 + fi * 16 + mloc;
    const size_t rowbase = (size_t)i * ldc;
#pragma unroll
    for (int fj = 0; fj < 4; ++fj) {
      const int nb = n0 + wc * 64 + fj * 16 + ng;
      *(float4*)((float*)Cout + rowbase + nb) =
          make_float4(acc[fi][fj][0], acc[fi][fj][1], acc[fi][fj][2], acc[fi][fj][3]);
    }
  }
#undef STAGE256
}

// ---------------------------------------------------------------------------
// bf16 MFMA NT GEMM, 64x64 tile, BK=64, 4 waves (per-layer GEMMs).
// 3-buffer, 2-ahead, single barrier, counted vmcnt 8/4/0.
// FUSED REPACK (QKV call only, Kg != nullptr): the epilogue additionally
// writes Kg[h][512][96], Vgt[h][96][512], Vlt[h][96][VLT_LD] — bit-identical
// to the values written to Cout, eliminating the separate repack kernel.
// ---------------------------------------------------------------------------
__global__ __launch_bounds__(256) void gemm64_bf16_kernel(
    const unsigned short* __restrict__ A, const unsigned short* __restrict__ B,
    const float* __restrict__ bias, const float* __restrict__ res,
    void* __restrict__ Cout, int M, int N, int K, int ldc, int act, int outbf,
    const int* __restrict__ ntt, unsigned short* __restrict__ Kg,
    unsigned short* __restrict__ Vgt, unsigned short* __restrict__ Vlt) {
  __shared__ __align__(16) unsigned short As[3 * 4096];
  __shared__ __align__(16) unsigned short Bs[3 * 4096];
  const int t = threadIdx.x;
  const int w = t >> 6, l = t & 63;
  const int n0 = blockIdx.x * 64, i0 = blockIdx.y * 64;
  const int wr = w >> 1, wc = w & 1;
  const int lr = l & 15;
  const int koff = (l >> 4) * 8;
  const int T = Kg ? (ntt[0] + 1) : 1;

  f32x4 acc[2][2] = {};

  const int srow = t >> 2;
  const int scol = (t & 3) * 8;
  const unsigned short* Ag = A + (size_t)(i0 + srow) * K + scol;
  const unsigned short* Bg = B + (size_t)(n0 + srow) * K + scol;
  const int lo0 = (w << 9);
  const int lo1 = 2048 + (w << 9);

#define STAGE64(buf, k0)                                      \
  do {                                                        \
    gload_lds16(Ag + (k0), &As[(buf) * 4096 + lo0]);          \
    gload_lds16(Ag + (k0) + 32, &As[(buf) * 4096 + lo1]);     \
    gload_lds16(Bg + (k0), &Bs[(buf) * 4096 + lo0]);          \
    gload_lds16(Bg + (k0) + 32, &Bs[(buf) * 4096 + lo1]);     \
  } while (0)

#define COMPUTE64(buf)                                                        \
  do {                                                                        \
    const unsigned short* Ab = &As[(buf) * 4096];                             \
    const unsigned short* Bb = &Bs[(buf) * 4096];                             \
    bf16x8 af[2][2], bfr[2][2];                                               \
    _Pragma("unroll") for (int fi = 0; fi < 2; ++fi)                          \
      _Pragma("unroll") for (int kk = 0; kk < 2; ++kk)                        \
          af[fi][kk] = *(const bf16x8*)&Ab[kk * 2048 + (wr * 32 + fi * 16 + lr) * 32 + koff]; \
    _Pragma("unroll") for (int fj = 0; fj < 2; ++fj)                          \
      _Pragma("unroll") for (int kk = 0; kk < 2; ++kk)                        \
          bfr[fj][kk] = *(const bf16x8*)&Bb[kk * 2048 + (wc * 32 + fj * 16 + lr) * 32 + koff]; \
    _Pragma("unroll") for (int fi = 0; fi < 2; ++fi)                          \
      _Pragma("unroll") for (int fj = 0; fj < 2; ++fj)                        \
        _Pragma("unroll") for (int kk = 0; kk < 2; ++kk)                      \
            acc[fi][fj] = __builtin_amdgcn_mfma_f32_16x16x32_bf16(            \
                bfr[fj][kk], af[fi][kk], acc[fi][fj], 0, 0, 0);               \
  } while (0)

  const int nt = K >> 6;
  STAGE64(0, 0);
  if (nt > 1) STAGE64(1, 64);
  for (int tt = 0; tt < nt; ++tt) {
    __builtin_amdgcn_s_barrier();
    if (tt + 2 < nt) {
      STAGE64((tt + 2) % 3, (tt + 2) << 6);
      asm volatile("s_waitcnt vmcnt(8)" ::: "memory");
    } else if (tt + 1 < nt) {
      asm volatile("s_waitcnt vmcnt(4)" ::: "memory");
    } else {
      asm volatile("s_waitcnt vmcnt(0)" ::: "memory");
    }
    __builtin_amdgcn_sched_barrier(0);
    COMPUTE64(tt % 3);
    __builtin_amdgcn_sched_barrier(0);
  }

  const int mloc = l & 15, ng = (l >> 4) * 4;
#pragma unroll
  for (int fi = 0; fi < 2; ++fi) {
    const int i = i0 + wr * 32 + fi * 16 + mloc;
    const size_t rowbase = (size_t)i * ldc;
#pragma unroll
    for (int fj = 0; fj < 2; ++fj) {
      const int nb = n0 + wc * 32 + fj * 16 + ng;
      float z0 = acc[fi][fj][0], z1 = acc[fi][fj][1];
      float z2 = acc[fi][fj][2], z3 = acc[fi][fj][3];
      if (bias) {
        float4 bv = *(const float4*)(bias + nb);
        z0 += bv.x; z1 += bv.y; z2 += bv.z; z3 += bv.w;
      }
      if (act) {
        z0 = gelu_exact(z0); z1 = gelu_exact(z1);
        z2 = gelu_exact(z2); z3 = gelu_exact(z3);
      }
      if (res) {
        float4 rv = *(const float4*)(res + rowbase + nb);
        z0 += rv.x; z1 += rv.y; z2 += rv.z; z3 += rv.w;
      }
      if (outbf) {
        u16x4 o;
        o[0] = f2bf(z0); o[1] = f2bf(z1); o[2] = f2bf(z2); o[3] = f2bf(z3);
        *(u16x4*)((unsigned short*)Cout + rowbase + nb) = o;
        if (Kg) {
          // fused repack: i = absolute position p, nb..nb+3 = QKV columns
          if (nb >= DMODEL && nb < 2 * DMODEL) {
            // K columns -> Kg for global positions
            if (i % T == 0) {
              const int gg = i / T;
              if (gg < MAXLEN_C) {
                const int kcol = nb - DMODEL;
                const int h = kcol / HDIM, d = kcol - h * HDIM;
                *(u16x4*)&Kg[((size_t)h * 512 + gg) * HDIM + d] = o;
              }
            }
          } else if (nb >= 2 * DMODEL) {
            // V columns -> Vlt (all positions) and Vgt (global positions)
            const int vcol = nb - 2 * DMODEL;
            const int h = vcol / HDIM, d = vcol - h * HDIM;
            Vlt[((size_t)h * HDIM + d + 0) * VLT_LD + i] = o[0];
            Vlt[((size_t)h * HDIM + d + 1) * VLT_LD + i] = o[1];
            Vlt[((size_t)h * HDIM + d + 2) * VLT_LD + i] = o[2];
            Vlt[((size_t)h * HDIM + d + 3) * VLT_LD + i] = o[3];
            if (i % T == 0) {
              const int gg = i / T;
              if (gg < MAXLEN_C) {
                Vgt[((size_t)h * HDIM + d + 0) * 512 + gg] = o[0];
                Vgt[((size_t)h * HDIM + d + 1) * 512 + gg] = o[1];
                Vgt[((size_t)h * HDIM + d + 2) * 512 + gg] = o[2];
                Vgt[((size_t)h * HDIM + d + 3) * 512 + gg] = o[3];
              }
            }
          }
        }
      } else {
        *(float4*)((float*)Cout + rowbase + nb) = make_float4(z0, z1, z2, z3);
      }
    }
  }
#undef STAGE64
#undef COMPUTE64
}

// ---------------------------------------------------------------------------
// MFMA flash attention over the block-causal mask. setprio(1) around MFMA
// clusters (T5: 4 independent-phase waves per block -> m191 regime).
// ---------------------------------------------------------------------------
__global__ __launch_bounds__(256) void attn_flash_kernel(
    const unsigned short* __restrict__ qkv, const unsigned short* __restrict__ Kg,
    const unsigned short* __restrict__ Vgt, const unsigned short* __restrict__ Vlt,
    const int* __restrict__ ntt, unsigned short* __restrict__ att) {
  __shared__ float Osh[4][96][17];
  __shared__ float Msh[4][16];
  __shared__ float Lsh[4][16];
  const int s = blockIdx.x, h = blockIdx.y;
  const int T = ntt[0] + 1;
  const int tid = threadIdx.x;
  const int w = tid >> 6, l = tid & 63;
  const int q15 = l & 15, grp = l >> 4;
  const int p0 = s * 16;
  const int p = p0 + q15;
  const int myTok = p / T;

  const unsigned short* qrow = qkv + (size_t)p * QKVD + h * HDIM + grp * 8;
  bf16x8 qf0 = *(const bf16x8*)(qrow);
  bf16x8 qf1 = *(const bf16x8*)(qrow + 32);
  bf16x8 qf2 = *(const bf16x8*)(qrow + 64);

  float m_run = M_INIT, l_run = 0.0f;
  f32x4 oacc[6] = {};

  const int gmax = (p0 + 15) / T;
  const int KP = (gmax >> 5) + 1;
  const unsigned short* KgH = Kg + (size_t)h * 512 * 96;
  const unsigned short* VgH = Vgt + (size_t)h * 96 * 512;

  for (int kp = w; kp < KP; kp += 4) {
    f32x4 s0 = {}, s1 = {};
    const unsigned short* k0r = KgH + (size_t)(kp * 32 + q15) * 96 + grp * 8;
    const unsigned short* k1r = k0r + 16 * 96;
    {
      bf16x8 a0 = *(const bf16x8*)(k0r);
      bf16x8 a1 = *(const bf16x8*)(k1r);
      bf16x8 b0 = *(const bf16x8*)(k0r + 32);
      bf16x8 b1 = *(const bf16x8*)(k1r + 32);
      bf16x8 c0 = *(const bf16x8*)(k0r + 64);
      bf16x8 c1 = *(const bf16x8*)(k1r + 64);
      __builtin_amdgcn_s_setprio(1);
      s0 = __builtin_amdgcn_mfma_f32_16x16x32_bf16(a0, qf0, s0, 0, 0, 0);
      s1 = __builtin_amdgcn_mfma_f32_16x16x32_bf16(a1, qf0, s1, 0, 0, 0);
      s0 = __builtin_amdgcn_mfma_f32_16x16x32_bf16(b0, qf1, s0, 0, 0, 0);
      s1 = __builtin_amdgcn_mfma_f32_16x16x32_bf16(b1, qf1, s1, 0, 0, 0);
      s0 = __builtin_amdgcn_mfma_f32_16x16x32_bf16(c0, qf2, s0, 0, 0, 0);
      s1 = __builtin_amdgcn_mfma_f32_16x16x32_bf16(c1, qf2, s1, 0, 0, 0);
      __builtin_amdgcn_s_setprio(0);
    }
    float sc[8];
#pragma unroll
    for (int e = 0; e < 4; ++e) {
      int g = kp * 32 + grp * 4 + e;
      sc[e] = (g * T <= p) ? s0[e] * QK_SCALE : NEG_BIG;
      g += 16;
      sc[4 + e] = (g * T <= p) ? s1[e] * QK_SCALE : NEG_BIG;
    }
    float tmax = sc[0];
#pragma unroll
    for (int e = 1; e < 8; ++e) tmax = fmaxf(tmax, sc[e]);
    tmax = fmaxf(tmax, __shfl_xor(tmax, 16));
    tmax = fmaxf(tmax, __shfl_xor(tmax, 32));
    float mnew = fmaxf(m_run, tmax);
    float alpha = __expf(m_run - mnew);
    float pv[8], ps = 0.0f;
#pragma unroll
    for (int e = 0; e < 8; ++e) { pv[e] = __expf(sc[e] - mnew); ps += pv[e]; }
    ps += __shfl_xor(ps, 16);
    ps += __shfl_xor(ps, 32);
    l_run = l_run * alpha + ps;
    m_run = mnew;
#pragma unroll
    for (int dt = 0; dt < 6; ++dt) oacc[dt] *= alpha;
    unsigned int pk0[2], pk1[2];
    pk0[0] = pack2bf(pv[0], pv[1]); pk0[1] = pack2bf(pv[2], pv[3]);
    pk1[0] = pack2bf(pv[4], pv[5]); pk1[1] = pack2bf(pv[6], pv[7]);
    union { unsigned int u[4]; bf16x8 v; } pf;
#pragma unroll
    for (int w2 = 0; w2 < 4; ++w2) {
      int src = (((grp & 1) << 1) + (w2 >> 1)) * 16 + q15;
      int y0 = __shfl((int)pk0[w2 & 1], src);
      int y1 = __shfl((int)pk1[w2 & 1], src);
      pf.u[w2] = (grp >> 1) ? (unsigned int)y1 : (unsigned int)y0;
    }
    __builtin_amdgcn_s_setprio(1);
#pragma unroll
    for (int dt = 0; dt < 6; ++dt) {
      bf16x8 vf = *(const bf16x8*)(VgH + (size_t)(dt * 16 + q15) * 512 + kp * 32 + grp * 8);
      oacc[dt] = __builtin_amdgcn_mfma_f32_16x16x32_bf16(vf, pf.v, oacc[dt], 0, 0, 0);
    }
    __builtin_amdgcn_s_setprio(0);
  }

  if (w == 3) {
    f32x4 s0 = {};
    const unsigned short* kl = qkv + (size_t)(p0 + q15) * QKVD + DMODEL + h * HDIM + grp * 8;
    __builtin_amdgcn_s_setprio(1);
    s0 = __builtin_amdgcn_mfma_f32_16x16x32_bf16(*(const bf16x8*)(kl), qf0, s0, 0, 0, 0);
    s0 = __builtin_amdgcn_mfma_f32_16x16x32_bf16(*(const bf16x8*)(kl + 32), qf1, s0, 0, 0, 0);
    s0 = __builtin_amdgcn_mfma_f32_16x16x32_bf16(*(const bf16x8*)(kl + 64), qf2, s0, 0, 0, 0);
    __builtin_amdgcn_s_setprio(0);
    float sc[4];
#pragma unroll
    for (int e = 0; e < 4; ++e) {
      int pk = p0 + grp * 4 + e;
      bool ok = (pk / T == myTok) && (pk % T != 0) && (pk <= p);
      sc[e] = ok ? s0[e] * QK_SCALE : NEG_BIG;
    }
    float tmax = fmaxf(fmaxf(sc[0], sc[1]), fmaxf(sc[2], sc[3]));
    tmax = fmaxf(tmax, __shfl_xor(tmax, 16));
    tmax = fmaxf(tmax, __shfl_xor(tmax, 32));
    float mnew = fmaxf(m_run, tmax);
    float alpha = __expf(m_run - mnew);
    float pv[4], ps = 0.0f;
#pragma unroll
    for (int e = 0; e < 4; ++e) { pv[e] = __expf(sc[e] - mnew); ps += pv[e]; }
    ps += __shfl_xor(ps, 16);
    ps += __shfl_xor(ps, 32);
    l_run = l_run * alpha + ps;
    m_run = mnew;
#pragma unroll
    for (int dt = 0; dt < 6; ++dt) oacc[dt] *= alpha;
    unsigned int pk0[2];
    pk0[0] = pack2bf(pv[0], pv[1]); pk0[1] = pack2bf(pv[2], pv[3]);
    union { unsigned int u[4]; bf16x8 v; } pf;
#pragma unroll
    for (int w2 = 0; w2 < 4; ++w2) {
      int src = (((grp & 1) << 1) + (w2 >> 1)) * 16 + q15;
      int y0 = __shfl((int)pk0[w2 & 1], src);
      pf.u[w2] = (grp >> 1) ? 0u : (unsigned int)y0;
    }
    __builtin_amdgcn_s_setprio(1);
#pragma unroll
    for (int dt = 0; dt < 6; ++dt) {
      bf16x8 vf = *(const bf16x8*)(Vlt + ((size_t)h * 96 + dt * 16 + q15) * VLT_LD + p0 + grp * 8);
      oacc[dt] = __builtin_amdgcn_mfma_f32_16x16x32_bf16(vf, pf.v, oacc[dt], 0, 0, 0);
    }
    __builtin_amdgcn_s_setprio(0);
  }

  if (l < 16) { Msh[w][l] = m_run; Lsh[w][l] = l_run; }
#pragma unroll
  for (int dt = 0; dt < 6; ++dt)
#pragma unroll
    for (int e = 0; e < 4; ++e)
      Osh[w][dt * 16 + grp * 4 + e][q15] = oacc[dt][e];
  __syncthreads();

  {
    const int q = tid & 15, dg = tid >> 4;
    float m0 = Msh[0][q], m1 = Msh[1][q], m2 = Msh[2][q], m3 = Msh[3][q];
    float ms = fmaxf(fmaxf(m0, m1), fmaxf(m2, m3));
    float c0 = __expf(m0 - ms), c1 = __expf(m1 - ms);
    float c2 = __expf(m2 - ms), c3 = __expf(m3 - ms);
    float lsum = c0 * Lsh[0][q] + c1 * Lsh[1][q] + c2 * Lsh[2][q] + c3 * Lsh[3][q];
    float rinv = 1.0f / lsum;
    unsigned short* orow = att + (size_t)(p0 + q) * DMODEL + h * HDIM;
#pragma unroll
    for (int j = 0; j < 6; ++j) {
      int d = dg * 6 + j;
      float o = c0 * Osh[0][d][q] + c1 * Osh[1][d][q] +
                c2 * Osh[2][d][q] + c3 * Osh[3][d][q];
      orow[d] = f2bf(o * rinv);
    }
  }
}

// ---------------------------------------------------------------------------
// Value head stage 2: values[i] = sum_f F1[i][f] * w2[f] + b2[0]  (F1 bf16)
// ---------------------------------------------------------------------------
__global__ __launch_bounds__(256) void v2_kernel(
    const unsigned short* __restrict__ F1, const float* __restrict__ w2,
    const float* __restrict__ b2, float* __restrict__ out) {
  __shared__ float red[4];
  const int row = blockIdx.x;
  const int tid = threadIdx.x;
  float s = 0.0f;
  const unsigned short* xr = F1 + (size_t)row * FFDIM;
  for (int f = tid; f < FFDIM; f += 256) s += bf2f(xr[f]) * w2[f];
  for (int o = 32; o; o >>= 1) s += __shfl_xor(s, o);
  if ((tid & 63) == 0) red[tid >> 6] = s;
  __syncthreads();
  if (tid == 0) out[row] = red[0] + red[1] + red[2] + red[3] + b2[0];
}

// ---------------------------------------------------------------------------
extern "C" void kernel_launch(void* const* d_in, const int* in_sizes, int n_in,
                              void* d_out, int out_size, void* d_ws, size_t ws_size,
                              hipStream_t stream) {
  const float* se      = (const float*)d_in[0];
  const float* pe      = (const float*)d_in[2];
  const float* th      = (const float*)d_in[3];
  const float* w_qkv   = (const float*)d_in[4];
  const float* b_qkv   = (const float*)d_in[5];
  const float* w_out   = (const float*)d_in[6];
  const float* b_out   = (const float*)d_in[7];
  const float* ln1_g   = (const float*)d_in[8];
  const float* ln1_b   = (const float*)d_in[9];
  const float* ln2_g   = (const float*)d_in[10];
  const float* ln2_b   = (const float*)d_in[11];
  const float* w_ff1   = (const float*)d_in[12];
  const float* b_ff1   = (const float*)d_in[13];
  const float* w_ff2   = (const float*)d_in[14];
  const float* b_ff2   = (const float*)d_in[15];
  const float* fn_g    = (const float*)d_in[16];
  const float* fn_b    = (const float*)d_in[17];
  const float* w_pol   = (const float*)d_in[18];
  const float* w_v1    = (const float*)d_in[19];
  const float* b_v1    = (const float*)d_in[20];
  const float* w_v2    = (const float*)d_in[21];
  const float* b_v2    = (const float*)d_in[22];
  const int*   ntt     = (const int*)d_in[23];

  float* logits = (float*)d_out;
  float* values = logits + (size_t)S_TOT * VOCAB;

  const int nq = 3 * DMODEL * DMODEL, no = DMODEL * DMODEL;
  const int nf1 = FFDIM * DMODEL, nf2 = DMODEL * FFDIM;
  const int npol = VOCAB * DMODEL;

  // common activations layout
  char* p = (char*)d_ws;
  float* X             = (float*)p;          p += (size_t)S_TOT * DMODEL * 4;
  unsigned short* Ybf  = (unsigned short*)p; p += (size_t)S_TOT * DMODEL * 2;
  unsigned short* QKVb = (unsigned short*)p; p += (size_t)S_TOT * QKVD * 2;
  unsigned short* ATTb = (unsigned short*)p; p += (size_t)S_TOT * DMODEL * 2;
  unsigned short* F1b  = (unsigned short*)p; p += (size_t)S_TOT * FFDIM * 2;
  unsigned short* Kg   = (unsigned short*)p; p += (size_t)NHEAD * 512 * 96 * 2;
  unsigned short* Vgt  = (unsigned short*)p; p += (size_t)NHEAD * 96 * 512 * 2;
  unsigned short* Vlt  = (unsigned short*)p; p += (size_t)NHEAD * 96 * VLT_LD * 2;

  // big-ws path: all weights converted once
  const size_t wbytes = ((size_t)8 * (nq + no + nf1 + nf2) + npol + nf1) * 2;
  const size_t used   = (size_t)(p - (char*)d_ws);
  const bool bigws = ws_size >= used + wbytes + (1u << 20);

  unsigned short *WqA, *WoA, *Wf1A, *Wf2A, *WpolA, *Wv1A;
  if (bigws) {
    WqA   = (unsigned short*)p; p += (size_t)8 * nq * 2;
    WoA   = (unsigned short*)p; p += (size_t)8 * no * 2;
    Wf1A  = (unsigned short*)p; p += (size_t)8 * nf1 * 2;
    Wf2A  = (unsigned short*)p; p += (size_t)8 * nf2 * 2;
    WpolA = (unsigned short*)p; p += (size_t)npol * 2;
    Wv1A  = (unsigned short*)p;
  } else {
    WqA   = (unsigned short*)p; p += (size_t)nq * 2;
    WoA   = (unsigned short*)p; p += (size_t)no * 2;
    Wf1A  = (unsigned short*)p; p += (size_t)nf1 * 2;
    Wf2A  = (unsigned short*)p; p += (size_t)nf2 * 2;
    WpolA = (unsigned short*)p;  // POL_CHUNK*DMODEL chunk buffer
    Wv1A  = Wf1A;
  }

  dim3 blk(256);

  if (bigws) {
    const int t0 = 8 * nq, t1 = 8 * no, t2 = 8 * nf1, t3 = 8 * nf2;
    const long total = (long)t0 + t1 + t2 + t3 + npol + nf1;
    cvt6_kernel<<<dim3((unsigned)((total / 4 + 255) / 256)), blk, 0, stream>>>(
        w_qkv, w_out, w_ff1, w_ff2, w_pol, w_v1,
        WqA, WoA, Wf1A, Wf2A, WpolA, Wv1A,
        t0, t1, t2, t3, npol, nf1);
  }

  embed_kernel<<<dim3((S_TOT * DMODEL + 255) / 256), blk, 0, stream>>>(se, pe, th, ntt, X);

  for (int l = 0; l < 8; ++l) {
    const unsigned short* pWq  = bigws ? WqA  + (size_t)l * nq  : WqA;
    const unsigned short* pWo  = bigws ? WoA  + (size_t)l * no  : WoA;
    const unsigned short* pWf1 = bigws ? Wf1A + (size_t)l * nf1 : Wf1A;
    const unsigned short* pWf2 = bigws ? Wf2A + (size_t)l * nf2 : Wf2A;
    if (!bigws) {
      const int ncvt4 = (nq + no + nf1 + nf2) / 4;
      cvt4_kernel<<<dim3((ncvt4 + 255) / 256), blk, 0, stream>>>(
          w_qkv + (size_t)l * nq, w_out + (size_t)l * no,
          w_ff1 + (size_t)l * nf1, w_ff2 + (size_t)l * nf2,
          WqA, WoA, Wf1A, Wf2A, nq, no, nf1, nf2);
    }

    ln_bf_kernel<<<dim3(S_TOT), blk, 0, stream>>>(X, ln1_g + l * DMODEL, ln1_b + l * DMODEL, Ybf);
    // QKV GEMM with fused K/V repack (writes QKVb + Kg + Vgt + Vlt)
    gemm64_bf16_kernel<<<dim3(QKVD / 64, S_TOT / 64), blk, 0, stream>>>(
        Ybf, pWq, b_qkv + (size_t)l * 3 * DMODEL, nullptr, QKVb,
        S_TOT, QKVD, DMODEL, QKVD, 0, 1, ntt, Kg, Vgt, Vlt);
    attn_flash_kernel<<<dim3(S_TOT / 16, NHEAD), blk, 0, stream>>>(
        QKVb, Kg, Vgt, Vlt, ntt, ATTb);
    gemm64_bf16_kernel<<<dim3(DMODEL / 64, S_TOT / 64), blk, 0, stream>>>(
        ATTb, pWo, b_out + (size_t)l * DMODEL, X, X,
        S_TOT, DMODEL, DMODEL, DMODEL, 0, 0, nullptr, nullptr, nullptr, nullptr);

    ln_bf_kernel<<<dim3(S_TOT), blk, 0, stream>>>(X, ln2_g + l * DMODEL, ln2_b + l * DMODEL, Ybf);
    gemm64_bf16_kernel<<<dim3(FFDIM / 64, S_TOT / 64), blk, 0, stream>>>(
        Ybf, pWf1, b_ff1 + (size_t)l * FFDIM, nullptr, F1b,
        S_TOT, FFDIM, DMODEL, FFDIM, 1, 1, nullptr, nullptr, nullptr, nullptr);
    gemm64_bf16_kernel<<<dim3(DMODEL / 64, S_TOT / 64), blk, 0, stream>>>(
        F1b, pWf2, b_ff2 + (size_t)l * DMODEL, X, X,
        S_TOT, DMODEL, FFDIM, DMODEL, 0, 0, nullptr, nullptr, nullptr, nullptr);
  }

  ln_bf_kernel<<<dim3(S_TOT), blk, 0, stream>>>(X, fn_g, fn_b, Ybf);

  if (bigws) {
    // 256x128 tile, 8 waves, 2000 blocks (2000 % 8 == 0), m-fastest swizzle
    gemm256_bf16_kernel<<<dim3((S_TOT / 256) * (VOCAB / 128)), dim3(512), 0, stream>>>(
        Ybf, WpolA, logits, S_TOT, VOCAB, DMODEL, VOCAB);
  } else {
    for (int c = 0; c < VOCAB / POL_CHUNK; ++c) {
      cvt_kernel<<<dim3((POL_CHUNK * DMODEL / 4 + 255) / 256), blk, 0, stream>>>(
          w_pol + (size_t)c * POL_CHUNK * DMODEL, WpolA, POL_CHUNK * DMODEL);
      gemm_bf16_kernel<<<dim3(POL_CHUNK / 128, S_TOT / 128), blk, 0, stream>>>(
          Ybf, WpolA, nullptr, nullptr, logits + (size_t)c * POL_CHUNK,
          S_TOT, POL_CHUNK, DMODEL, VOCAB, 0, 0, 0);
    }
  }

  // value head
  gemm64_bf16_kernel<<<dim3(FFDIM / 64, S_TOT / 64), blk, 0, stream>>>(
      Ybf, Wv1A, b_v1, nullptr, F1b, S_TOT, FFDIM, DMODEL, FFDIM, 1, 1,
      nullptr, nullptr, nullptr, nullptr);
  v2_kernel<<<dim3(S_TOT), blk, 0, stream>>>(F1b, w_v2, b_v2, values);
}